// Round 1
// baseline (550.993 us; speedup 1.0000x reference)
//
#include <hip/hip_runtime.h>
#include <cmath>

#define NTOK 3072
#define NBLK 3

__device__ __forceinline__ float sig(float v) { return 1.0f / (1.0f + expf(-v)); }

// ---------------- row LayerNorm over 128 (one wave per row) ----------------
__global__ __launch_bounds__(256) void ln_rows_kernel(const float* __restrict__ src,
                                                      float* __restrict__ dst)
{
    int row  = blockIdx.x * 4 + (threadIdx.x >> 6);
    int lane = threadIdx.x & 63;
    const float* s = src + (size_t)row * 128;
    float x0 = s[lane], x1 = s[lane + 64];
    float sum = x0 + x1;
#pragma unroll
    for (int m = 1; m < 64; m <<= 1) sum += __shfl_xor(sum, m);
    float mean = sum * (1.0f / 128.0f);
    float d0 = x0 - mean, d1 = x1 - mean;
    float v = d0 * d0 + d1 * d1;
#pragma unroll
    for (int m = 1; m < 64; m <<= 1) v += __shfl_xor(v, m);
    float rs = 1.0f / sqrtf(v * (1.0f / 128.0f) + 1e-5f);
    float* d = dst + (size_t)row * 128;
    d[lane] = d0 * rs;
    d[lane + 64] = d1 * rs;
}

// ---------------- pair-bias precompute: zb[i][q][kk][h] for local windows ----------------
// zb = (LN(plm)*g + b) @ wz  ==  LN(plm) @ (g .* wz)  +  (b @ wz)
__global__ __launch_bounds__(256) void zbias_kernel(const float* __restrict__ plm,
                                                    const float* __restrict__ zg,
                                                    const float* __restrict__ zbeta,
                                                    const float* __restrict__ wz,
                                                    float* __restrict__ zball)
{
    __shared__ __align__(16) float wzg[NBLK][16][4];
    __shared__ __align__(16) float zb0[NBLK][4];
    int tid = threadIdx.x;
    if (tid < NBLK * 64) {
        int i = tid >> 6, rem = tid & 63, c = rem >> 2, h = rem & 3;
        wzg[i][c][h] = zg[i * 16 + c] * wz[(i * 16 + c) * 4 + h];
    }
    if (tid < NBLK * 4) {
        int i = tid >> 2, h = tid & 3;
        float s = 0.0f;
        for (int c = 0; c < 16; c++) s += zbeta[i * 16 + c] * wz[(i * 16 + c) * 4 + h];
        zb0[i][h] = s;
    }
    __syncthreads();
    int j = blockIdx.x;
    int kstart = max(0, j * 32 - 48);
    int W = min(NTOK, j * 32 + 80) - kstart;
    int q0 = j * 32 + blockIdx.y * 8;
    for (int p = tid; p < 8 * 128; p += 256) {
        int qi = p >> 7, kk = p & 127;
        if (kk >= W) continue;
        int q = q0 + qi;
        const float* src = plm + ((size_t)q * NTOK + (size_t)(kstart + kk)) * 16;
        float x[16];
        *(float4*)(x + 0)  = *(const float4*)(src + 0);
        *(float4*)(x + 4)  = *(const float4*)(src + 4);
        *(float4*)(x + 8)  = *(const float4*)(src + 8);
        *(float4*)(x + 12) = *(const float4*)(src + 12);
        float s = 0.0f;
#pragma unroll
        for (int c = 0; c < 16; c++) s += x[c];
        float mean = s * (1.0f / 16.0f);
        float v = 0.0f;
#pragma unroll
        for (int c = 0; c < 16; c++) { float d = x[c] - mean; v += d * d; }
        float rs = 1.0f / sqrtf(v * (1.0f / 16.0f) + 1e-5f);
#pragma unroll
        for (int c = 0; c < 16; c++) x[c] = (x[c] - mean) * rs;
#pragma unroll
        for (int i = 0; i < NBLK; i++) {
            float o0 = zb0[i][0], o1 = zb0[i][1], o2 = zb0[i][2], o3 = zb0[i][3];
#pragma unroll
            for (int c = 0; c < 16; c++) {
                float xv = x[c];
                float4 w4 = *(const float4*)wzg[i][c];
                o0 = fmaf(xv, w4.x, o0);
                o1 = fmaf(xv, w4.y, o1);
                o2 = fmaf(xv, w4.z, o2);
                o3 = fmaf(xv, w4.w, o3);
            }
            float4 o4 = make_float4(o0, o1, o2, o3);
            *(float4*)&zball[(((size_t)i * NTOK + q) * 128 + kk) * 4] = o4;
        }
    }
}

// ---------------- generic dual-GEMM with fused epilogue ----------------
// tile: 32 rows x 128 cols, 256 threads; acc1 = A1@W1 (+bias1 under sigmoid), acc2 = A2@W2
enum { EPI_X = 0, EPI_GATE = 1, EPI_FF = 2, EPI_FINAL = 3 };

template <int EPI, int K1, int K2>
__global__ __launch_bounds__(256) void dual_gemm_kernel(
    const float* __restrict__ A1, const float* __restrict__ W1, const float* __restrict__ bias1,
    const float* __restrict__ A2, const float* __restrict__ W2,
    const float* __restrict__ aux, float* __restrict__ outp, int M)
{
    __shared__ __align__(16) float As1[32][K1];
    __shared__ __align__(16) float As2[32][K2];
    int row0 = blockIdx.x * 32;
    int cb = blockIdx.y * 128;
    int tid = threadIdx.x;
    for (int idx4 = tid; idx4 < 32 * K1 / 4; idx4 += 256) {
        int fo = idx4 * 4;
        int r = fo / K1, c = fo % K1;
        *(float4*)&As1[r][c] = *(const float4*)&A1[(size_t)(row0 + r) * K1 + c];
    }
    for (int idx4 = tid; idx4 < 32 * K2 / 4; idx4 += 256) {
        int fo = idx4 * 4;
        int r = fo / K2, c = fo % K2;
        *(float4*)&As2[r][c] = *(const float4*)&A2[(size_t)(row0 + r) * K2 + c];
    }
    __syncthreads();
    int lane = tid & 63, wv = tid >> 6;
    int c0 = cb + lane * 2;
    int r0 = wv * 8;
    float acc1[8][2] = {};
    float acc2[8][2] = {};
    for (int k = 0; k < K1; k += 4) {
        float2 w0 = *(const float2*)&W1[(size_t)(k + 0) * M + c0];
        float2 w1 = *(const float2*)&W1[(size_t)(k + 1) * M + c0];
        float2 w2 = *(const float2*)&W1[(size_t)(k + 2) * M + c0];
        float2 w3 = *(const float2*)&W1[(size_t)(k + 3) * M + c0];
#pragma unroll
        for (int rr = 0; rr < 8; rr++) {
            float4 a = *(const float4*)&As1[r0 + rr][k];
            acc1[rr][0] = fmaf(a.x, w0.x, fmaf(a.y, w1.x, fmaf(a.z, w2.x, fmaf(a.w, w3.x, acc1[rr][0]))));
            acc1[rr][1] = fmaf(a.x, w0.y, fmaf(a.y, w1.y, fmaf(a.z, w2.y, fmaf(a.w, w3.y, acc1[rr][1]))));
        }
    }
    for (int k = 0; k < K2; k += 4) {
        float2 w0 = *(const float2*)&W2[(size_t)(k + 0) * M + c0];
        float2 w1 = *(const float2*)&W2[(size_t)(k + 1) * M + c0];
        float2 w2 = *(const float2*)&W2[(size_t)(k + 2) * M + c0];
        float2 w3 = *(const float2*)&W2[(size_t)(k + 3) * M + c0];
#pragma unroll
        for (int rr = 0; rr < 8; rr++) {
            float4 a = *(const float4*)&As2[r0 + rr][k];
            acc2[rr][0] = fmaf(a.x, w0.x, fmaf(a.y, w1.x, fmaf(a.z, w2.x, fmaf(a.w, w3.x, acc2[rr][0]))));
            acc2[rr][1] = fmaf(a.x, w0.y, fmaf(a.y, w1.y, fmaf(a.z, w2.y, fmaf(a.w, w3.y, acc2[rr][1]))));
        }
    }
#pragma unroll
    for (int rr = 0; rr < 8; rr++) {
        int r = row0 + r0 + rr;
#pragma unroll
        for (int cc = 0; cc < 2; cc++) {
            int c = c0 + cc;
            float v1 = acc1[rr][cc], v2 = acc2[rr][cc];
            float o;
            if constexpr (EPI == EPI_X)     o = sig(v1 + bias1[c]) * aux[(size_t)r * M + c] + v2;
            if constexpr (EPI == EPI_GATE)  o = sig(v1 + bias1[c]) * v2;
            if constexpr (EPI == EPI_FF)    o = v1 * sig(v1) * v2;            // silu(a@ff1)*(a@ff2)
            if constexpr (EPI == EPI_FINAL) o = aux[(size_t)r * M + c] + sig(v1 + bias1[c]) * v2;
            outp[(size_t)r * M + c] = o;
        }
    }
}

// ---------------- q/k/v/g projection into [N][512] ----------------
__global__ __launch_bounds__(256) void qkvg_kernel(const float* __restrict__ x,
                                                   const float* __restrict__ wq, const float* __restrict__ bq,
                                                   const float* __restrict__ wk, const float* __restrict__ wv,
                                                   const float* __restrict__ wg, float* __restrict__ outp)
{
    __shared__ __align__(16) float As[32][128];
    int row0 = blockIdx.x * 32;
    int mat = blockIdx.y;
    const float* Wm = (mat == 0) ? wq : (mat == 1) ? wk : (mat == 2) ? wv : wg;
    int tid = threadIdx.x;
    for (int idx4 = tid; idx4 < 1024; idx4 += 256) {
        int fo = idx4 * 4;
        int r = fo >> 7, c = fo & 127;
        *(float4*)&As[r][c] = *(const float4*)&x[(size_t)(row0 + r) * 128 + c];
    }
    __syncthreads();
    int lane = tid & 63, wv2 = tid >> 6;
    int c0 = lane * 2;
    int r0 = wv2 * 8;
    float acc[8][2] = {};
    for (int k = 0; k < 128; k += 4) {
        float2 w0 = *(const float2*)&Wm[(size_t)(k + 0) * 128 + c0];
        float2 w1 = *(const float2*)&Wm[(size_t)(k + 1) * 128 + c0];
        float2 w2 = *(const float2*)&Wm[(size_t)(k + 2) * 128 + c0];
        float2 w3 = *(const float2*)&Wm[(size_t)(k + 3) * 128 + c0];
#pragma unroll
        for (int rr = 0; rr < 8; rr++) {
            float4 a = *(const float4*)&As[r0 + rr][k];
            acc[rr][0] = fmaf(a.x, w0.x, fmaf(a.y, w1.x, fmaf(a.z, w2.x, fmaf(a.w, w3.x, acc[rr][0]))));
            acc[rr][1] = fmaf(a.x, w0.y, fmaf(a.y, w1.y, fmaf(a.z, w2.y, fmaf(a.w, w3.y, acc[rr][1]))));
        }
    }
#pragma unroll
    for (int rr = 0; rr < 8; rr++) {
        int r = row0 + r0 + rr;
#pragma unroll
        for (int cc = 0; cc < 2; cc++) {
            int c = c0 + cc;
            float b = (mat == 0) ? bq[c] : 0.0f;
            outp[(size_t)r * 512 + mat * 128 + c] = acc[rr][cc] + b;
        }
    }
}

// ---------------- local attention: one (query-block, head) per workgroup ----------------
__global__ __launch_bounds__(256) void attn_kernel(const float* __restrict__ qkvg,
                                                   const float* __restrict__ zb,
                                                   float* __restrict__ outp)
{
    __shared__ float qs[32][33];
    __shared__ float ks[128][33];
    __shared__ float vs[128][33];
    __shared__ float ps[32][129];
    int j = blockIdx.x, h = blockIdx.y;
    int q0 = j * 32;
    int kstart = max(0, q0 - 48);
    int W = min(NTOK, q0 + 80) - kstart;
    int tid = threadIdx.x;
    {
        int qi = tid >> 3, d = (tid & 7) * 4;
        float4 t = *(const float4*)&qkvg[(size_t)(q0 + qi) * 512 + h * 32 + d];
        qs[qi][d] = t.x; qs[qi][d + 1] = t.y; qs[qi][d + 2] = t.z; qs[qi][d + 3] = t.w;
    }
    for (int idx = tid; idx < W * 8; idx += 256) {
        int kk = idx >> 3, d = (idx & 7) * 4;
        const float* base = &qkvg[(size_t)(kstart + kk) * 512 + 128 + h * 32 + d];
        float4 t = *(const float4*)base;
        ks[kk][d] = t.x; ks[kk][d + 1] = t.y; ks[kk][d + 2] = t.z; ks[kk][d + 3] = t.w;
        float4 u = *(const float4*)(base + 128);
        vs[kk][d] = u.x; vs[kk][d + 1] = u.y; vs[kk][d + 2] = u.z; vs[kk][d + 3] = u.w;
    }
    __syncthreads();
    int qi = tid & 31, kg = tid >> 5;
    float qreg[32];
#pragma unroll
    for (int d = 0; d < 32; d++) qreg[d] = qs[qi][d];
    const float scale = 0.17677669529663687f;  // 1/sqrt(32)
    const float* zrow = zb + ((size_t)(q0 + qi) * 128) * 4 + h;
    for (int kk = kg; kk < W; kk += 8) {
        float acc = 0.0f;
#pragma unroll
        for (int d = 0; d < 32; d++) acc = fmaf(qreg[d], ks[kk][d], acc);
        ps[qi][kk] = fmaf(acc, scale, zrow[(size_t)kk * 4]);
    }
    __syncthreads();
    // softmax: 8 threads per row
    int row = tid >> 3, sub = tid & 7;
    float m = -3.0e38f;
    for (int kk = sub; kk < W; kk += 8) m = fmaxf(m, ps[row][kk]);
#pragma unroll
    for (int s2 = 1; s2 < 8; s2 <<= 1) m = fmaxf(m, __shfl_xor(m, s2));
    float ssum = 0.0f;
    for (int kk = sub; kk < W; kk += 8) { float e = expf(ps[row][kk] - m); ps[row][kk] = e; ssum += e; }
#pragma unroll
    for (int s2 = 1; s2 < 8; s2 <<= 1) ssum += __shfl_xor(ssum, s2);
    float rinv = 1.0f / ssum;
    for (int kk = sub; kk < W; kk += 8) ps[row][kk] *= rinv;
    __syncthreads();
    // o = p @ v, gated by sigmoid(g)
    int dg = tid >> 5, d0 = dg * 4;
    float o0 = 0, o1 = 0, o2 = 0, o3 = 0;
    for (int kk = 0; kk < W; kk++) {
        float p = ps[qi][kk];
        o0 = fmaf(p, vs[kk][d0 + 0], o0);
        o1 = fmaf(p, vs[kk][d0 + 1], o1);
        o2 = fmaf(p, vs[kk][d0 + 2], o2);
        o3 = fmaf(p, vs[kk][d0 + 3], o3);
    }
    float4 g4 = *(const float4*)&qkvg[(size_t)(q0 + qi) * 512 + 384 + h * 32 + d0];
    float4 r;
    r.x = o0 * sig(g4.x); r.y = o1 * sig(g4.y); r.z = o2 * sig(g4.z); r.w = o3 * sig(g4.w);
    *(float4*)&outp[(size_t)(q0 + qi) * 128 + h * 32 + d0] = r;
}

extern "C" void kernel_launch(void* const* d_in, const int* in_sizes, int n_in,
                              void* d_out, int out_size, void* d_ws, size_t ws_size,
                              hipStream_t stream)
{
    const float* ql       = (const float*)d_in[0];
    const float* cl       = (const float*)d_in[1];
    const float* plm      = (const float*)d_in[2];
    const float* ada_g_w  = (const float*)d_in[3];
    const float* ada_g_b  = (const float*)d_in[4];
    const float* ada_b_w  = (const float*)d_in[5];
    const float* wq       = (const float*)d_in[6];
    const float* bq       = (const float*)d_in[7];
    const float* wk       = (const float*)d_in[8];
    const float* wv       = (const float*)d_in[9];
    const float* z_ln_g   = (const float*)d_in[10];
    const float* z_ln_b   = (const float*)d_in[11];
    const float* wz       = (const float*)d_in[12];
    const float* wg       = (const float*)d_in[13];
    const float* wo       = (const float*)d_in[14];
    const float* sg_w     = (const float*)d_in[15];
    const float* sg_b     = (const float*)d_in[16];
    const float* ada2_g_w = (const float*)d_in[17];
    const float* ada2_g_b = (const float*)d_in[18];
    const float* ada2_b_w = (const float*)d_in[19];
    const float* ff1      = (const float*)d_in[20];
    const float* ff2      = (const float*)d_in[21];
    const float* ff3      = (const float*)d_in[22];
    const float* sg2_w    = (const float*)d_in[23];
    const float* sg2_b    = (const float*)d_in[24];

    float* ws = (float*)d_ws;
    const size_t NC = (size_t)NTOK * 128;
    float* s_ln   = ws;
    float* a      = ws + NC;
    float* ln_a   = ws + 2 * NC;
    float* x      = ws + 3 * NC;
    float* attn   = ws + 4 * NC;
    float* bout   = ws + 5 * NC;
    float* y      = ws + 6 * NC;
    float* qkvg   = ws + 7 * NC;   // N x 512
    float* ff     = ws + 11 * NC;  // N x 256
    float* zb     = ws + 13 * NC;  // 3 x N x 128 x 4

    hipMemcpyAsync(a, ql, NC * sizeof(float), hipMemcpyDeviceToDevice, stream);
    ln_rows_kernel<<<NTOK / 4, 256, 0, stream>>>(cl, s_ln);
    zbias_kernel<<<dim3(96, 4), 256, 0, stream>>>(plm, z_ln_g, z_ln_b, wz, zb);

    for (int i = 0; i < NBLK; i++) {
        size_t o128 = (size_t)i * 128 * 128;
        size_t ob   = (size_t)i * 128;
        size_t o256 = (size_t)i * 128 * 256;

        ln_rows_kernel<<<NTOK / 4, 256, 0, stream>>>(a, ln_a);
        // x = sigmoid(s_ln@ada_g_w + ada_g_b) * ln_a + s_ln@ada_b_w
        dual_gemm_kernel<EPI_X, 128, 128><<<dim3(96, 1), 256, 0, stream>>>(
            s_ln, ada_g_w + o128, ada_g_b + ob, s_ln, ada_b_w + o128, ln_a, x, 128);
        qkvg_kernel<<<dim3(96, 4), 256, 0, stream>>>(x, wq + o128, bq + ob, wk + o128, wv + o128, wg + o128, qkvg);
        attn_kernel<<<dim3(96, 4), 256, 0, stream>>>(qkvg, zb + (size_t)i * 4 * NC, attn);
        // b_out = sigmoid(s_ln@sg_w + sg_b) * (attn @ wo)
        dual_gemm_kernel<EPI_GATE, 128, 128><<<dim3(96, 1), 256, 0, stream>>>(
            s_ln, sg_w + o128, sg_b + ob, attn, wo + o128, nullptr, bout, 128);
        // y = sigmoid(s_ln@ada2_g_w + ada2_g_b) * ln_a + s_ln@ada2_b_w
        dual_gemm_kernel<EPI_X, 128, 128><<<dim3(96, 1), 256, 0, stream>>>(
            s_ln, ada2_g_w + o128, ada2_g_b + ob, s_ln, ada2_b_w + o128, ln_a, y, 128);
        // ff = silu(y@ff1) * (y@ff2)
        dual_gemm_kernel<EPI_FF, 128, 128><<<dim3(96, 2), 256, 0, stream>>>(
            y, ff1 + o256, nullptr, y, ff2 + o256, nullptr, ff, 256);
        // a' = b_out + sigmoid(s_ln@sg2_w + sg2_b) * (ff @ ff3)
        float* aout = (i == NBLK - 1) ? (float*)d_out : a;
        dual_gemm_kernel<EPI_FINAL, 128, 256><<<dim3(96, 1), 256, 0, stream>>>(
            s_ln, sg2_w + o128, sg2_b + ob, ff, ff3 + (size_t)i * 256 * 128, bout, aout, 128);
    }
}

// Round 2
// 546.135 us; speedup vs baseline: 1.0089x; 1.0089x over previous
//
#include <hip/hip_runtime.h>
#include <cmath>

#define NTOK 3072
#define NBLK 3

__device__ __forceinline__ float sig(float v) { return 1.0f / (1.0f + expf(-v)); }

// ---------- staging helper: R rows x K cols into LDS ----------
template<int R, int K>
__device__ __forceinline__ void stage_rows(const float* __restrict__ A, int row0,
                                           float (*As)[K], int tid, int nthr) {
    for (int i4 = tid; i4 < R * K / 4; i4 += nthr) {
        int fo = i4 * 4;
        int r = fo / K, c = fo % K;
        *(float4*)&As[r][c] = *(const float4*)&A[(size_t)(row0 + r) * K + c];
    }
}

// ---------- register tile: 2 rows x 2 cols per thread ----------
template<int K>
__device__ __forceinline__ void gemm_tile(const float (*As)[K], const float* __restrict__ W,
                                          int M, int c0, int r0, float acc[2][2]) {
    for (int k = 0; k < K; k += 4) {
        float2 w0 = *(const float2*)&W[(k + 0) * M + c0];
        float2 w1 = *(const float2*)&W[(k + 1) * M + c0];
        float2 w2 = *(const float2*)&W[(k + 2) * M + c0];
        float2 w3 = *(const float2*)&W[(k + 3) * M + c0];
#pragma unroll
        for (int rr = 0; rr < 2; rr++) {
            float4 a = *(const float4*)&As[r0 + rr][k];
            acc[rr][0] = fmaf(a.x, w0.x, fmaf(a.y, w1.x, fmaf(a.z, w2.x, fmaf(a.w, w3.x, acc[rr][0]))));
            acc[rr][1] = fmaf(a.x, w0.y, fmaf(a.y, w1.y, fmaf(a.z, w2.y, fmaf(a.w, w3.y, acc[rr][1]))));
        }
    }
}

// ---------- LN of two inputs (cl -> s_ln, ql -> ln_a) ----------
__global__ __launch_bounds__(256) void ln2_kernel(const float* __restrict__ cl,
                                                  const float* __restrict__ ql,
                                                  float* __restrict__ s_ln,
                                                  float* __restrict__ ln_a)
{
    const float* src = blockIdx.y ? ql : cl;
    float* dst       = blockIdx.y ? ln_a : s_ln;
    int row  = blockIdx.x * 4 + (threadIdx.x >> 6);
    int lane = threadIdx.x & 63;
    const float* s = src + (size_t)row * 128;
    float x0 = s[lane], x1 = s[lane + 64];
    float sum = x0 + x1;
#pragma unroll
    for (int m = 1; m < 64; m <<= 1) sum += __shfl_xor(sum, m);
    float mean = sum * (1.0f / 128.0f);
    float d0 = x0 - mean, d1 = x1 - mean;
    float v = d0 * d0 + d1 * d1;
#pragma unroll
    for (int m = 1; m < 64; m <<= 1) v += __shfl_xor(v, m);
    float rs = 1.0f / sqrtf(v * (1.0f / 128.0f) + 1e-5f);
    float* d = dst + (size_t)row * 128;
    d[lane] = d0 * rs;
    d[lane + 64] = d1 * rs;
}

// ---------- pair-bias: zb[i][h][q][kk] for the local windows ----------
__global__ __launch_bounds__(256) void zbias_kernel(const float* __restrict__ plm,
                                                    const float* __restrict__ zg,
                                                    const float* __restrict__ zbeta,
                                                    const float* __restrict__ wz,
                                                    float* __restrict__ zball)
{
    __shared__ __align__(16) float wzg[NBLK][16][4];
    __shared__ __align__(16) float zb0[NBLK][4];
    int tid = threadIdx.x;
    if (tid < NBLK * 64) {
        int i = tid >> 6, rem = tid & 63, c = rem >> 2, h = rem & 3;
        wzg[i][c][h] = zg[i * 16 + c] * wz[(i * 16 + c) * 4 + h];
    }
    if (tid < NBLK * 4) {
        int i = tid >> 2, h = tid & 3;
        float s = 0.0f;
        for (int c = 0; c < 16; c++) s += zbeta[i * 16 + c] * wz[(i * 16 + c) * 4 + h];
        zb0[i][h] = s;
    }
    __syncthreads();
    int j = blockIdx.x;
    int kstart = max(0, j * 32 - 48);
    int W = min(NTOK, j * 32 + 80) - kstart;
    int q0 = j * 32 + blockIdx.y * 4;
    for (int p = tid; p < 4 * 128; p += 256) {
        int qi = p >> 7, kk = p & 127;
        if (kk >= W) continue;
        int q = q0 + qi;
        const float* src = plm + ((size_t)q * NTOK + (size_t)(kstart + kk)) * 16;
        float x[16];
        *(float4*)(x + 0)  = *(const float4*)(src + 0);
        *(float4*)(x + 4)  = *(const float4*)(src + 4);
        *(float4*)(x + 8)  = *(const float4*)(src + 8);
        *(float4*)(x + 12) = *(const float4*)(src + 12);
        float s = 0.0f;
#pragma unroll
        for (int c = 0; c < 16; c++) s += x[c];
        float mean = s * (1.0f / 16.0f);
        float v = 0.0f;
#pragma unroll
        for (int c = 0; c < 16; c++) { float d = x[c] - mean; v += d * d; }
        float rs = 1.0f / sqrtf(v * (1.0f / 16.0f) + 1e-5f);
#pragma unroll
        for (int c = 0; c < 16; c++) x[c] = (x[c] - mean) * rs;
#pragma unroll
        for (int i = 0; i < NBLK; i++) {
            float o0 = zb0[i][0], o1 = zb0[i][1], o2 = zb0[i][2], o3 = zb0[i][3];
#pragma unroll
            for (int c = 0; c < 16; c++) {
                float xv = x[c];
                float4 w4 = *(const float4*)wzg[i][c];
                o0 = fmaf(xv, w4.x, o0);
                o1 = fmaf(xv, w4.y, o1);
                o2 = fmaf(xv, w4.z, o2);
                o3 = fmaf(xv, w4.w, o3);
            }
            size_t base = ((size_t)(i * 4) * NTOK + q) * 128 + kk;
            zball[base]                       = o0;
            zball[base + (size_t)NTOK * 128]  = o1;
            zball[base + (size_t)NTOK * 256]  = o2;
            zball[base + (size_t)NTOK * 384]  = o3;
        }
    }
}

// ---------- x / y adaLN kernel (blockIdx.y: 0 -> x, 1 -> y) ----------
__global__ __launch_bounds__(256) void xy_kernel(const float* __restrict__ s_ln,
                                                 const float* __restrict__ ln_a,
                                                 const float* __restrict__ Wg1, const float* __restrict__ bg1,
                                                 const float* __restrict__ Wb1,
                                                 const float* __restrict__ Wg2, const float* __restrict__ bg2,
                                                 const float* __restrict__ Wb2,
                                                 float* __restrict__ out1, float* __restrict__ out2)
{
    __shared__ __align__(16) float As[8][128];
    const float* Wg = blockIdx.y ? Wg2 : Wg1;
    const float* bg = blockIdx.y ? bg2 : bg1;
    const float* Wb = blockIdx.y ? Wb2 : Wb1;
    float* outp     = blockIdx.y ? out2 : out1;
    int row0 = blockIdx.x * 8;
    int tid = threadIdx.x;
    stage_rows<8, 128>(s_ln, row0, As, tid, 256);
    __syncthreads();
    int lane = tid & 63, wv = tid >> 6;
    int c0 = lane * 2, r0 = wv * 2;
    float a1[2][2] = {}, a2[2][2] = {};
    gemm_tile<128>(As, Wg, 128, c0, r0, a1);
    gemm_tile<128>(As, Wb, 128, c0, r0, a2);
    float2 bgv = *(const float2*)&bg[c0];
#pragma unroll
    for (int rr = 0; rr < 2; rr++) {
        int r = row0 + r0 + rr;
        float2 ln2v = *(const float2*)&ln_a[(size_t)r * 128 + c0];
        float2 o;
        o.x = sig(a1[rr][0] + bgv.x) * ln2v.x + a2[rr][0];
        o.y = sig(a1[rr][1] + bgv.y) * ln2v.y + a2[rr][1];
        *(float2*)&outp[(size_t)r * 128 + c0] = o;
    }
}

// ---------- q/k/v/g projection ----------
__global__ __launch_bounds__(256) void qkvg_kernel(const float* __restrict__ x,
                                                   const float* __restrict__ wq, const float* __restrict__ bq,
                                                   const float* __restrict__ wk, const float* __restrict__ wv,
                                                   const float* __restrict__ wg, float* __restrict__ outp)
{
    __shared__ __align__(16) float As[8][128];
    int row0 = blockIdx.x * 8;
    int mat = blockIdx.y;
    const float* Wm = (mat == 0) ? wq : (mat == 1) ? wk : (mat == 2) ? wv : wg;
    int tid = threadIdx.x;
    stage_rows<8, 128>(x, row0, As, tid, 256);
    __syncthreads();
    int lane = tid & 63, wv2 = tid >> 6;
    int c0 = lane * 2, r0 = wv2 * 2;
    float acc[2][2] = {};
    gemm_tile<128>(As, Wm, 128, c0, r0, acc);
    float b0 = (mat == 0) ? bq[c0] : 0.0f;
    float b1 = (mat == 0) ? bq[c0 + 1] : 0.0f;
#pragma unroll
    for (int rr = 0; rr < 2; rr++) {
        int r = row0 + r0 + rr;
        float2 o = make_float2(acc[rr][0] + b0, acc[rr][1] + b1);
        *(float2*)&outp[(size_t)r * 512 + mat * 128 + c0] = o;
    }
}

// ---------- local attention: one (query-block, head) per workgroup, 512 thr ----------
__global__ __launch_bounds__(512) void attn_kernel(const float* __restrict__ qkvg,
                                                   const float* __restrict__ zb,
                                                   float* __restrict__ outp)
{
    __shared__ float qs[32][33];
    __shared__ float ks[128][36];
    __shared__ float vs[128][36];
    __shared__ float ps[32][129];
    __shared__ float os[32][36];
    int j = blockIdx.x, h = blockIdx.y;
    int q0 = j * 32;
    int kstart = max(0, q0 - 48);
    int W = min(NTOK, q0 + 80) - kstart;
    int tid = threadIdx.x;
    if (tid < 256) {
        int qi = tid >> 3, d = (tid & 7) * 4;
        float4 t = *(const float4*)&qkvg[(size_t)(q0 + qi) * 512 + h * 32 + d];
        qs[qi][d] = t.x; qs[qi][d + 1] = t.y; qs[qi][d + 2] = t.z; qs[qi][d + 3] = t.w;
    }
    for (int idx = tid; idx < W * 8; idx += 512) {
        int kk = idx >> 3, d = (idx & 7) * 4;
        const float* base = &qkvg[(size_t)(kstart + kk) * 512 + 128 + h * 32 + d];
        float4 t = *(const float4*)base;
        ks[kk][d] = t.x; ks[kk][d + 1] = t.y; ks[kk][d + 2] = t.z; ks[kk][d + 3] = t.w;
        float4 u = *(const float4*)(base + 128);
        vs[kk][d] = u.x; vs[kk][d + 1] = u.y; vs[kk][d + 2] = u.z; vs[kk][d + 3] = u.w;
    }
    __syncthreads();
    int qi = tid & 31, kg = tid >> 5;      // kg in 0..15
    float qreg[32];
#pragma unroll
    for (int d = 0; d < 32; d++) qreg[d] = qs[qi][d];
    const float scale = 0.17677669529663687f;  // 1/sqrt(32)
    const float* zrow = zb + ((size_t)h * NTOK + q0 + qi) * 128;
    for (int kk = kg; kk < W; kk += 16) {
        float acc = 0.0f;
#pragma unroll
        for (int d4 = 0; d4 < 8; d4++) {
            float4 kv = *(const float4*)&ks[kk][d4 * 4];
            acc = fmaf(qreg[d4 * 4 + 0], kv.x, acc);
            acc = fmaf(qreg[d4 * 4 + 1], kv.y, acc);
            acc = fmaf(qreg[d4 * 4 + 2], kv.z, acc);
            acc = fmaf(qreg[d4 * 4 + 3], kv.w, acc);
        }
        ps[qi][kk] = fmaf(acc, scale, zrow[kk]);
    }
    __syncthreads();
    // softmax: 16 threads per row
    int row = tid >> 4, sub = tid & 15;
    float m = -3.0e38f;
    for (int kk = sub; kk < W; kk += 16) m = fmaxf(m, ps[row][kk]);
#pragma unroll
    for (int s2 = 1; s2 < 16; s2 <<= 1) m = fmaxf(m, __shfl_xor(m, s2));
    float ssum = 0.0f;
    for (int kk = sub; kk < W; kk += 16) { float e = expf(ps[row][kk] - m); ps[row][kk] = e; ssum += e; }
#pragma unroll
    for (int s2 = 1; s2 < 16; s2 <<= 1) ssum += __shfl_xor(ssum, s2);
    float rinv = 1.0f / ssum;
    for (int kk = sub; kk < W; kk += 16) ps[row][kk] *= rinv;
    __syncthreads();
    // o = p @ v
    int dg = tid >> 5, d0 = dg * 2;        // 16 groups x 2 dims
    float o0 = 0.0f, o1 = 0.0f;
    for (int kk = 0; kk < W; kk++) {
        float p = ps[qi][kk];
        float2 v2 = *(const float2*)&vs[kk][d0];
        o0 = fmaf(p, v2.x, o0);
        o1 = fmaf(p, v2.y, o1);
    }
    *(float2*)&os[qi][d0] = make_float2(o0, o1);
    __syncthreads();
    if (tid < 256) {
        int r = tid >> 3, seg = (tid & 7) * 4;
        float4 ov = *(const float4*)&os[r][seg];
        float4 g4 = *(const float4*)&qkvg[(size_t)(q0 + r) * 512 + 384 + h * 32 + seg];
        float4 o;
        o.x = ov.x * sig(g4.x); o.y = ov.y * sig(g4.y);
        o.z = ov.z * sig(g4.z); o.w = ov.w * sig(g4.w);
        *(float4*)&outp[(size_t)(q0 + r) * 128 + h * 32 + seg] = o;
    }
}

// ---------- bout (y==0) and ff halves (y==1,2) ----------
__global__ __launch_bounds__(256) void boutff_kernel(const float* __restrict__ s_ln,
                                                     const float* __restrict__ attn,
                                                     const float* __restrict__ ybuf,
                                                     const float* __restrict__ sg_w, const float* __restrict__ sg_b,
                                                     const float* __restrict__ wo,
                                                     const float* __restrict__ ff1, const float* __restrict__ ff2,
                                                     float* __restrict__ bout, float* __restrict__ ffb)
{
    __shared__ __align__(16) float As1[8][128];
    __shared__ __align__(16) float As2[8][128];
    int row0 = blockIdx.x * 8;
    int by = blockIdx.y;
    int tid = threadIdx.x;
    if (by == 0) {
        stage_rows<8, 128>(s_ln, row0, As1, tid, 256);
        stage_rows<8, 128>(attn, row0, As2, tid, 256);
    } else {
        stage_rows<8, 128>(ybuf, row0, As1, tid, 256);
    }
    __syncthreads();
    int lane = tid & 63, wv = tid >> 6;
    int c0 = lane * 2, r0 = wv * 2;
    float a1[2][2] = {}, a2[2][2] = {};
    if (by == 0) {
        gemm_tile<128>(As1, sg_w, 128, c0, r0, a1);
        gemm_tile<128>(As2, wo, 128, c0, r0, a2);
        float2 bv = *(const float2*)&sg_b[c0];
#pragma unroll
        for (int rr = 0; rr < 2; rr++) {
            int r = row0 + r0 + rr;
            float2 o;
            o.x = sig(a1[rr][0] + bv.x) * a2[rr][0];
            o.y = sig(a1[rr][1] + bv.y) * a2[rr][1];
            *(float2*)&bout[(size_t)r * 128 + c0] = o;
        }
    } else {
        int ch = (by - 1) * 128 + c0;
        gemm_tile<128>(As1, ff1, 256, ch, r0, a1);
        gemm_tile<128>(As1, ff2, 256, ch, r0, a2);
#pragma unroll
        for (int rr = 0; rr < 2; rr++) {
            int r = row0 + r0 + rr;
            float2 o;
            o.x = a1[rr][0] * sig(a1[rr][0]) * a2[rr][0];
            o.y = a1[rr][1] * sig(a1[rr][1]) * a2[rr][1];
            *(float2*)&ffb[(size_t)r * 256 + ch] = o;
        }
    }
}

// ---------- final: a_new = bout + sig(s_ln@sg2+b)*(ff@ff3); emit LN(a_new) or d_out ----------
template<bool LAST>
__global__ __launch_bounds__(256) void final_kernel(const float* __restrict__ s_ln,
                                                    const float* __restrict__ ffb,
                                                    const float* __restrict__ sg2_w, const float* __restrict__ sg2_b,
                                                    const float* __restrict__ ff3,
                                                    const float* __restrict__ bout,
                                                    float* __restrict__ outp)
{
    __shared__ __align__(16) float As1[8][128];
    __shared__ __align__(16) float As2[8][256];
    int row0 = blockIdx.x * 8;
    int tid = threadIdx.x;
    stage_rows<8, 128>(s_ln, row0, As1, tid, 256);
    stage_rows<8, 256>(ffb, row0, As2, tid, 256);
    __syncthreads();
    int lane = tid & 63, wv = tid >> 6;
    int c0 = lane * 2, r0 = wv * 2;
    float a1[2][2] = {}, a2[2][2] = {};
    gemm_tile<128>(As1, sg2_w, 128, c0, r0, a1);
    gemm_tile<256>(As2, ff3, 128, c0, r0, a2);
    float2 bv = *(const float2*)&sg2_b[c0];
    float anew[2][2];
#pragma unroll
    for (int rr = 0; rr < 2; rr++) {
        int r = row0 + r0 + rr;
        float2 bo = *(const float2*)&bout[(size_t)r * 128 + c0];
        anew[rr][0] = bo.x + sig(a1[rr][0] + bv.x) * a2[rr][0];
        anew[rr][1] = bo.y + sig(a1[rr][1] + bv.y) * a2[rr][1];
    }
    if constexpr (LAST) {
#pragma unroll
        for (int rr = 0; rr < 2; rr++) {
            int r = row0 + r0 + rr;
            *(float2*)&outp[(size_t)r * 128 + c0] = make_float2(anew[rr][0], anew[rr][1]);
        }
    } else {
        // fused LN(a_new) -> ln_a; each wave owns 2 full rows (128 cols across 64 lanes)
#pragma unroll
        for (int rr = 0; rr < 2; rr++) {
            int r = row0 + r0 + rr;
            float s = anew[rr][0] + anew[rr][1];
#pragma unroll
            for (int m = 1; m < 64; m <<= 1) s += __shfl_xor(s, m);
            float mean = s * (1.0f / 128.0f);
            float d0 = anew[rr][0] - mean, d1 = anew[rr][1] - mean;
            float v = d0 * d0 + d1 * d1;
#pragma unroll
            for (int m = 1; m < 64; m <<= 1) v += __shfl_xor(v, m);
            float rs = 1.0f / sqrtf(v * (1.0f / 128.0f) + 1e-5f);
            *(float2*)&outp[(size_t)r * 128 + c0] = make_float2(d0 * rs, d1 * rs);
        }
    }
}

extern "C" void kernel_launch(void* const* d_in, const int* in_sizes, int n_in,
                              void* d_out, int out_size, void* d_ws, size_t ws_size,
                              hipStream_t stream)
{
    const float* ql       = (const float*)d_in[0];
    const float* cl       = (const float*)d_in[1];
    const float* plm      = (const float*)d_in[2];
    const float* ada_g_w  = (const float*)d_in[3];
    const float* ada_g_b  = (const float*)d_in[4];
    const float* ada_b_w  = (const float*)d_in[5];
    const float* wq       = (const float*)d_in[6];
    const float* bq       = (const float*)d_in[7];
    const float* wk       = (const float*)d_in[8];
    const float* wv       = (const float*)d_in[9];
    const float* z_ln_g   = (const float*)d_in[10];
    const float* z_ln_b   = (const float*)d_in[11];
    const float* wz       = (const float*)d_in[12];
    const float* wg       = (const float*)d_in[13];
    const float* wo       = (const float*)d_in[14];
    const float* sg_w     = (const float*)d_in[15];
    const float* sg_b     = (const float*)d_in[16];
    const float* ada2_g_w = (const float*)d_in[17];
    const float* ada2_g_b = (const float*)d_in[18];
    const float* ada2_b_w = (const float*)d_in[19];
    const float* ff1      = (const float*)d_in[20];
    const float* ff2      = (const float*)d_in[21];
    const float* ff3      = (const float*)d_in[22];
    const float* sg2_w    = (const float*)d_in[23];
    const float* sg2_b    = (const float*)d_in[24];

    float* ws = (float*)d_ws;
    const size_t NC = (size_t)NTOK * 128;
    float* s_ln = ws;
    float* ln_a = ws + NC;
    float* x    = ws + 2 * NC;
    float* attn = ws + 3 * NC;
    float* bout = ws + 4 * NC;
    float* ybuf = ws + 5 * NC;
    float* qkvg = ws + 6 * NC;    // N x 512
    float* ffb  = ws + 10 * NC;   // N x 256
    float* zb   = ws + 12 * NC;   // 3 x 4 x N x 128

    ln2_kernel<<<dim3(NTOK / 4, 2), 256, 0, stream>>>(cl, ql, s_ln, ln_a);
    zbias_kernel<<<dim3(96, 8), 256, 0, stream>>>(plm, z_ln_g, z_ln_b, wz, zb);

    for (int i = 0; i < NBLK; i++) {
        size_t o128 = (size_t)i * 128 * 128;
        size_t ob   = (size_t)i * 128;
        size_t o256 = (size_t)i * 128 * 256;

        xy_kernel<<<dim3(384, 2), 256, 0, stream>>>(
            s_ln, ln_a, ada_g_w + o128, ada_g_b + ob, ada_b_w + o128,
            ada2_g_w + o128, ada2_g_b + ob, ada2_b_w + o128, x, ybuf);
        qkvg_kernel<<<dim3(384, 4), 256, 0, stream>>>(
            x, wq + o128, bq + ob, wk + o128, wv + o128, wg + o128, qkvg);
        attn_kernel<<<dim3(96, 4), 512, 0, stream>>>(
            qkvg, zb + (size_t)(i * 4) * NC, attn);
        boutff_kernel<<<dim3(384, 3), 256, 0, stream>>>(
            s_ln, attn, ybuf, sg_w + o128, sg_b + ob, wo + o128,
            ff1 + o256, ff2 + o256, bout, ffb);
        if (i == NBLK - 1)
            final_kernel<true><<<384, 256, 0, stream>>>(
                s_ln, ffb, sg2_w + o128, sg2_b + ob, ff3 + (size_t)i * 256 * 128, bout, (float*)d_out);
        else
            final_kernel<false><<<384, 256, 0, stream>>>(
                s_ln, ffb, sg2_w + o128, sg2_b + ob, ff3 + (size_t)i * 256 * 128, bout, ln_a);
    }
}